// Round 4
// baseline (88.842 us; speedup 1.0000x reference)
//
#include <hip/hip_runtime.h>

#define Zdim 128
#define Ydim 512
#define Xdim 512
#define Pdim 15
#define NWt  19
#define CHUNK 32          // z-planes per block; 4 chunks

typedef __attribute__((ext_vector_type(2))) float f2;

// One thread per 2 consecutive x; marches CHUNK z-planes.
// float2 (not float4) halves per-thread state so the 15-deep history ring +
// A/B prefetch buffers fit in <=64 VGPRs -> 8 waves/SIMD (2048 thr/CU cap).
// - weights via wave-uniform global reads -> s_load into SGPRs (no LDS)
// - all 4 input loads share one 32-bit offset (imm offsets -4/-2048/-2052 B)
// - distance-1 A/B pipeline, parity made static by #pragma unroll 2
__global__ __launch_bounds__(256, 8) void spec_pred_kernel(
    const float* __restrict__ img,
    const float* __restrict__ wts,
    float* __restrict__ out)
{
    const int bid = blockIdx.x;
    const int zc  = bid >> 9;                           // 0..3 (512 blocks/chunk)
    const int id  = ((bid & 511) << 8) | threadIdx.x;   // 0..131071
    const int xg  = (id & 255) << 1;                    // x0 of the float2
    const int y   = id >> 8;

    const unsigned plane = (unsigned)Ydim * Xdim;       // 262144 elems
    const unsigned pix   = (unsigned)y * Xdim + xg;
    const int  z0 = zc * CHUNK;
    const bool hn = (y > 0);
    const bool hw = (xg > 0);

    f2 h[Pdim];                                         // spectral history ring
    if (z0 == 0) {
#pragma unroll
        for (int p = 0; p < Pdim; ++p) h[p] = f2{0.0f, 0.0f};
    } else {
#pragma unroll
        for (int p = 0; p < Pdim; ++p)
            h[p] = *(const f2*)(img + pix + (unsigned)(z0 - Pdim + p) * plane);
    }

    f2 cA, nA, cB, nB;
    float wA, qA, wB, qB;

    auto LOAD = [&](int z, f2& c, f2& n, float& we, float& qw) {
        const unsigned b = pix + (unsigned)z * plane;
        c  = *(const f2*)(img + b);
        n  = hn ? *(const f2*)(img + b - Xdim) : f2{0.0f, 0.0f};
        we = hw ? img[b - 1] : 0.0f;
        qw = (hn && hw) ? img[b - Xdim - 1] : 0.0f;
    };

    auto STEP = [&](int z, const f2& c, const f2& n, float we, float qw) {
        const float* wz = wts + z * NWt;                // uniform addr -> s_load
        const float w3 = wz[3] * (1.0f / 3.0f);
        const float a0 = wz[0] + w3, a1 = wz[1] + w3, a2 = wz[2] + w3;
        f2 pv, rv;
        // e = 0 (west/nw from scalar edge loads)
        {
            float a = a0 * n[0];
            a = fmaf(a1, we, a);
            a = fmaf(a2, qw, a);
#pragma unroll
            for (int p = 0; p < Pdim; ++p) a = fmaf(wz[4 + p], h[p][0], a);
            a = fminf(fmaxf(a, -32768.0f), 32767.0f);
            pv[0] = a; rv[0] = c[0] - a;
        }
        // e = 1 (west/nw from in-vector neighbors)
        {
            float a = a0 * n[1];
            a = fmaf(a1, c[0], a);
            a = fmaf(a2, n[0], a);
#pragma unroll
            for (int p = 0; p < Pdim; ++p) a = fmaf(wz[4 + p], h[p][1], a);
            a = fminf(fmaxf(a, -32768.0f), 32767.0f);
            pv[1] = a; rv[1] = c[1] - a;
        }
        const unsigned ob = pix + (unsigned)z * plane;
        __builtin_nontemporal_store(pv, (f2*)(out + ob));
        __builtin_nontemporal_store(rv, (f2*)(out + (unsigned)Zdim * plane + ob));
#pragma unroll
        for (int p = 0; p < Pdim - 1; ++p) h[p] = h[p + 1];
        h[Pdim - 1] = c;
    };

    LOAD(z0, cA, nA, wA, qA);
#pragma unroll 2
    for (int i = 0; i < CHUNK - 1; ++i) {               // parity static via unroll 2
        if (i & 1) { LOAD(z0 + i + 1, cA, nA, wA, qA); STEP(z0 + i, cB, nB, wB, qB); }
        else       { LOAD(z0 + i + 1, cB, nB, wB, qB); STEP(z0 + i, cA, nA, wA, qA); }
    }
    STEP(z0 + CHUNK - 1, cB, nB, wB, qB);               // CHUNK-1 = 31 odd -> B
}

extern "C" void kernel_launch(void* const* d_in, const int* in_sizes, int n_in,
                              void* d_out, int out_size, void* d_ws, size_t ws_size,
                              hipStream_t stream) {
    const float* img = (const float*)d_in[0];
    const float* wts = (const float*)d_in[1];
    float* out = (float*)d_out;

    const int grid = 512 * (Zdim / CHUNK);   // 2048 blocks of 256 threads
    spec_pred_kernel<<<grid, 256, 0, stream>>>(img, wts, out);
}

// Round 5
// 74.470 us; speedup vs baseline: 1.1930x; 1.1930x over previous
//
#include <hip/hip_runtime.h>

#define Zdim 128
#define Ydim 512
#define Xdim 512
#define Pdim 15
#define NWt  19
#define CHUNK 32          // z-planes per block; 4 chunks

typedef __attribute__((ext_vector_type(4))) float f4;
struct F4 { float v[4]; };

__device__ __forceinline__ F4 ld4(const float* p) {
    f4 t = *(const f4*)p;
    F4 r; r.v[0] = t[0]; r.v[1] = t[1]; r.v[2] = t[2]; r.v[3] = t[3];
    return r;
}

// One thread per 4 consecutive x; marches CHUNK z-planes.
// - 15-deep register history ring, FULLY static (unroll 15: 30 = 2*15, 15%3==0
//   so both ring and the 3 rotating prefetch buffers need zero movs)
// - weights via wave-uniform global reads -> s_load into SGPRs (no LDS)
// - west/nw via __shfl_up from the lane-1 neighbor's vectors; only lane 0
//   (row-half boundary, xg==256) keeps a 1-lane masked prefetched edge load
// - distance-2 software prefetch pipeline, nontemporal f4 stores
// - XCD-aware block remap: bid%8 == XCD; each XCD owns 32 consecutive
//   y-pairs per z-chunk so north-halo reads hit the local L2
__global__ __launch_bounds__(256, 4) void spec_pred_kernel(
    const float* __restrict__ img,
    const float* __restrict__ wts,
    float* __restrict__ out)
{
    const int bid = blockIdx.x;
    const int zc  = bid >> 8;                          // 0..3
    const int r8  = bid & 255;
    const int yb  = ((r8 & 7) << 5) | (r8 >> 3);       // XCD-contiguous y-pair
    const int id  = (yb << 8) | threadIdx.x;           // 0..65535
    const int xg  = (id & 127) << 2;                   // x0 of the float4
    const int y   = id >> 7;

    const unsigned plane = (unsigned)Ydim * Xdim;
    const unsigned pix   = (unsigned)y * Xdim + xg;
    const float* ip = img + pix;
    float* pp = out + pix;
    float* rp = out + (unsigned)Zdim * plane + pix;

    const int  z0 = zc * CHUNK;
    const bool hn = (y > 0);
    const bool hw = (xg > 0);
    const bool l0 = (threadIdx.x & 63) == 0;           // wave lane 0

    F4 h[Pdim];                                        // spectral history ring
    if (z0 == 0) {
#pragma unroll
        for (int p = 0; p < Pdim; ++p) h[p] = F4{{0, 0, 0, 0}};
    } else {
#pragma unroll
        for (int p = 0; p < Pdim; ++p)
            h[p] = ld4(ip + (unsigned)(z0 - Pdim + p) * plane);
    }

    F4 cb[3], nb[3];                                   // rotating load buffers
    float wb[3], qb[3];                                // lane-0 edge values

    auto LOAD = [&](int z, int b) {
        const float* p0 = ip + (unsigned)z * plane;
        cb[b] = ld4(p0);
        nb[b] = hn ? ld4(p0 - Xdim) : F4{{0, 0, 0, 0}};
        wb[b] = (l0 && hw)       ? p0[-1]        : 0.0f;   // 1 active lane
        qb[b] = (l0 && hw && hn) ? p0[-Xdim - 1] : 0.0f;   // 1 active lane
    };

    auto STEP = [&](int z, int b) {
        const float* wz = wts + z * NWt;               // uniform addr -> s_load
        const float w3 = wz[3] * (1.0f / 3.0f);
        const float a0 = wz[0] + w3, a1 = wz[1] + w3, a2 = wz[2] + w3;
        // west / northwest from lane-1's vectors (lane 0: prefetched edges)
        float we = __shfl_up(cb[b].v[3], 1);
        float qw = __shfl_up(nb[b].v[3], 1);
        if (l0) { we = wb[b]; qw = qb[b]; }
        f4 pv, rv;
#pragma unroll
        for (int e = 0; e < 4; ++e) {
            const float vn = nb[b].v[e];
            float a = wz[4] * h[0].v[e];
#pragma unroll
            for (int p = 1; p < Pdim; ++p) a = fmaf(wz[4 + p], h[p].v[e], a);
            a = fmaf(a0, vn, a);
            // shfl results consumed last -> latency hidden under the FMA chain
            a = fmaf(a1, e ? cb[b].v[e - 1] : we, a);
            a = fmaf(a2, e ? nb[b].v[e - 1] : qw, a);
            a = fminf(fmaxf(a, -32768.0f), 32767.0f);
            pv[e] = a;
            rv[e] = cb[b].v[e] - a;
        }
        __builtin_nontemporal_store(pv, (f4*)(pp + (unsigned)z * plane));
        __builtin_nontemporal_store(rv, (f4*)(rp + (unsigned)z * plane));
#pragma unroll
        for (int p = 0; p < Pdim - 1; ++p) h[p] = h[p + 1];
        h[Pdim - 1] = cb[b];
    };

    LOAD(z0 + 0, 0);
    LOAD(z0 + 1, 1);
#pragma unroll 15
    for (int i = 0; i < CHUNK - 2; ++i) {              // 30 iters = 2*15
        LOAD(z0 + i + 2, (i + 2) % 3);                 // distance-2 prefetch
        STEP(z0 + i, i % 3);
    }
    STEP(z0 + CHUNK - 2, (CHUNK - 2) % 3);
    STEP(z0 + CHUNK - 1, (CHUNK - 1) % 3);
}

extern "C" void kernel_launch(void* const* d_in, const int* in_sizes, int n_in,
                              void* d_out, int out_size, void* d_ws, size_t ws_size,
                              hipStream_t stream) {
    const float* img = (const float*)d_in[0];
    const float* wts = (const float*)d_in[1];
    float* out = (float*)d_out;

    const int grid = 256 * (Zdim / CHUNK);   // 1024 blocks of 256 threads
    spec_pred_kernel<<<grid, 256, 0, stream>>>(img, wts, out);
}

// Round 6
// 68.741 us; speedup vs baseline: 1.2924x; 1.0833x over previous
//
#include <hip/hip_runtime.h>

#define Zdim 128
#define Ydim 512
#define Xdim 512
#define Pdim 15
#define NWt  19
#define CHUNK 64          // z-planes per block; 2 chunks -> only ONE history-preload boundary

typedef __attribute__((ext_vector_type(4))) float f4;
struct F4 { float v[4]; };

__device__ __forceinline__ F4 ld4(const float* p) {
    f4 t = *(const f4*)p;
    F4 r; r.v[0] = t[0]; r.v[1] = t[1]; r.v[2] = t[2]; r.v[3] = t[3];
    return r;
}

// One thread per 4 consecutive x; marches CHUNK z-planes.
// - 15-deep register history ring, fully static (main loop 60 iters = 4*15,
//   15%3==0 so ring shifts and the 3 rotating prefetch buffers cost no movs;
//   the 2 remainder iterations are written out with constant indices so no
//   dynamic indexing -> no scratch)
// - weights via wave-uniform global reads -> s_load into SGPRs (no LDS)
// - west/nw via __shfl_up of lane-1's vectors; lane 0 keeps 1-lane masked loads
// - distance-2 prefetch, nontemporal f4 stores
// - XCD-aware remap: bid%8 == XCD; each XCD owns contiguous y so north-halo
//   reads hit the local L2
__global__ __launch_bounds__(256, 2) void spec_pred_kernel(
    const float* __restrict__ img,
    const float* __restrict__ wts,
    float* __restrict__ out)
{
    const int bid = blockIdx.x;
    const int zc  = bid >> 8;                          // 0..1
    const int r8  = bid & 255;
    const int yb  = ((r8 & 7) << 5) | (r8 >> 3);       // XCD-contiguous y-pair
    const int id  = (yb << 8) | threadIdx.x;           // 0..65535
    const int xg  = (id & 127) << 2;                   // x0 of the float4
    const int y   = id >> 7;

    const unsigned plane = (unsigned)Ydim * Xdim;
    const unsigned pix   = (unsigned)y * Xdim + xg;
    const float* ip = img + pix;
    float* pp = out + pix;
    float* rp = out + (unsigned)Zdim * plane + pix;

    const int  z0 = zc * CHUNK;
    const bool hn = (y > 0);
    const bool hw = (xg > 0);
    const bool l0 = (threadIdx.x & 63) == 0;           // wave lane 0

    F4 h[Pdim];                                        // spectral history ring
    if (z0 == 0) {
#pragma unroll
        for (int p = 0; p < Pdim; ++p) h[p] = F4{{0, 0, 0, 0}};
    } else {
#pragma unroll
        for (int p = 0; p < Pdim; ++p)
            h[p] = ld4(ip + (unsigned)(z0 - Pdim + p) * plane);
    }

    F4 cb[3], nb[3];                                   // rotating load buffers
    float wb[3], qb[3];                                // lane-0 edge values

    auto LOAD = [&](int z, int b) {
        const float* p0 = ip + (unsigned)z * plane;
        cb[b] = ld4(p0);
        nb[b] = hn ? ld4(p0 - Xdim) : F4{{0, 0, 0, 0}};
        wb[b] = (l0 && hw)       ? p0[-1]        : 0.0f;   // 1 active lane
        qb[b] = (l0 && hw && hn) ? p0[-Xdim - 1] : 0.0f;   // 1 active lane
    };

    auto STEP = [&](int z, int b) {
        const float* wz = wts + z * NWt;               // uniform addr -> s_load
        const float w3 = wz[3] * (1.0f / 3.0f);
        const float a0 = wz[0] + w3, a1 = wz[1] + w3, a2 = wz[2] + w3;
        float we = __shfl_up(cb[b].v[3], 1);
        float qw = __shfl_up(nb[b].v[3], 1);
        if (l0) { we = wb[b]; qw = qb[b]; }
        f4 pv, rv;
#pragma unroll
        for (int e = 0; e < 4; ++e) {
            const float vn = nb[b].v[e];
            float a = wz[4] * h[0].v[e];
#pragma unroll
            for (int p = 1; p < Pdim; ++p) a = fmaf(wz[4 + p], h[p].v[e], a);
            a = fmaf(a0, vn, a);
            a = fmaf(a1, e ? cb[b].v[e - 1] : we, a);
            a = fmaf(a2, e ? nb[b].v[e - 1] : qw, a);
            a = fminf(fmaxf(a, -32768.0f), 32767.0f);
            pv[e] = a;
            rv[e] = cb[b].v[e] - a;
        }
        __builtin_nontemporal_store(pv, (f4*)(pp + (unsigned)z * plane));
        __builtin_nontemporal_store(rv, (f4*)(rp + (unsigned)z * plane));
#pragma unroll
        for (int p = 0; p < Pdim - 1; ++p) h[p] = h[p + 1];
        h[Pdim - 1] = cb[b];
    };

    LOAD(z0 + 0, 0);
    LOAD(z0 + 1, 1);
#pragma unroll 15
    for (int i = 0; i < 60; ++i) {                     // 60 = 4*15, fully static
        LOAD(z0 + i + 2, (i + 2) % 3);                 // distance-2 prefetch
        STEP(z0 + i, i % 3);
    }
    // remainder iterations, constant indices (avoid dynamic %3 -> scratch)
    LOAD(z0 + 62, 2); STEP(z0 + 60, 0);
    LOAD(z0 + 63, 0); STEP(z0 + 61, 1);
    STEP(z0 + 62, 2);
    STEP(z0 + 63, 0);
}

extern "C" void kernel_launch(void* const* d_in, const int* in_sizes, int n_in,
                              void* d_out, int out_size, void* d_ws, size_t ws_size,
                              hipStream_t stream) {
    const float* img = (const float*)d_in[0];
    const float* wts = (const float*)d_in[1];
    float* out = (float*)d_out;

    const int grid = 256 * (Zdim / CHUNK);   // 512 blocks of 256 threads
    spec_pred_kernel<<<grid, 256, 0, stream>>>(img, wts, out);
}